// Round 11
// baseline (312.659 us; speedup 1.0000x reference)
//
#include <hip/hip_runtime.h>
#include <hip/hip_cooperative_groups.h>

namespace cg = cooperative_groups;

namespace {
constexpr int NA    = 5;
constexpr int NCELL = 361;            // 19*19
constexpr int NBOX  = 1805;           // NA * NCELL
constexpr int NBOXP = 1856;           // NBOX rounded up to 64
constexpr int TMAX  = 50;
constexpr float CONF_T = 0.5f;
constexpr float NMS_T  = 0.45f;
constexpr float IOU_T  = 0.5f;
constexpr int NWMAX   = 32;           // keep/remove words (29 needed)
constexpr int ROWPAD  = 1856;         // supT padded row dim
constexpr int SOA_STRIDE = NBOXP;
constexpr int SOA_ARR    = 8 * SOA_STRIDE;
constexpr int NGRP = 29;              // ceil(1856/64) 64-row groups
constexpr int NBLK = NGRP * 8;        // 232 blocks (co-resident: 2/CU cap=512)
// ws layout (bytes)
constexpr size_t WS_COUNT = 0;        // 4 ints: prop, corr, total, done
constexpr size_t WS_M     = 64;       // 8 ints
constexpr size_t WS_SOA   = 256;      // 6 * SOA_ARR floats = 356,352 B
constexpr size_t WS_SUP   = 360448;   // 8 * 32 * ROWPAD * 8 = 3,801,088 B
// LDS union: phase A skey[2048](16384) + sbox[NBOX]f4(28880) = 45264;
// phase C SoA 6*NBOXP*4 = 44544. max = 45264.
constexpr int SMEM_BYTES = 45264;
}

__device__ __constant__ float d_anchw[NA] = {1.3221f, 3.19275f, 5.05587f, 9.47112f, 11.2364f};
__device__ __constant__ float d_anchh[NA] = {1.73145f, 4.00944f, 8.09892f, 4.84053f, 10.0071f};

__device__ inline unsigned long long shflx64(unsigned long long v, int m) {
    int lo = __shfl_xor((int)(unsigned)(v & 0xffffffffull), m, 64);
    int hi = __shfl_xor((int)(unsigned)(v >> 32), m, 64);
    return ((unsigned long long)(unsigned)hi << 32) | (unsigned)lo;
}
// uniform-index 64-bit readlane: ~3 cyc vs ~60-80 cyc for ds_bpermute shuffles
__device__ inline unsigned long long rdlane64(unsigned long long v, int l) {
    unsigned lo = (unsigned)__builtin_amdgcn_readlane((int)(unsigned)(v & 0xffffffffull), l);
    unsigned hi = (unsigned)__builtin_amdgcn_readlane((int)(unsigned)(v >> 32), l);
    return ((unsigned long long)hi << 32) | lo;
}
// Barrier that waits ONLY on LDS (lgkmcnt(0)); global prefetch loads stay in
// flight across the barrier. 0xC07F = vmcnt(63)|expcnt(7)|lgkmcnt(0).
__device__ inline void barrier_lgkm() {
    __asm__ volatile("" ::: "memory");
    __builtin_amdgcn_s_waitcnt(0xC07F);
    __builtin_amdgcn_s_barrier();
    __asm__ volatile("" ::: "memory");
}

// ---- single cooperative kernel: phase A (blocks 0-7) decode+sort ->
// grid.sync -> phase B (all 232 blocks) chip-wide IoU mask -> grid.sync ->
// phase C (blocks 0-7) 16-wave two-barrier sweep + GT + finisher.
// Phase A/C internals are copies of the measured-correct k_decode_sort /
// Round-6 k_sweep; phase B is K2 with 64 rows/block. ----
__global__ __launch_bounds__(1024, 1) void k_all(
    const float* __restrict__ net, const float* __restrict__ tgt,
    float* __restrict__ soa, unsigned long long* __restrict__ supT,
    int* __restrict__ Marr, int* __restrict__ counters,
    float* __restrict__ out)
{
    __shared__ __align__(16) char smem[SMEM_BYTES];
    unsigned long long* const skey = (unsigned long long*)smem;       // 2048
    float4* const sbox = (float4*)(smem + 16384);                     // NBOX
    float* const X1s = (float*)(smem);
    float* const Y1s = (float*)(smem +     NBOXP * 4);
    float* const X2s = (float*)(smem + 2 * NBOXP * 4);
    float* const Y2s = (float*)(smem + 3 * NBOXP * 4);
    float* const Wss = (float*)(smem + 4 * NBOXP * 4);
    float* const Hss = (float*)(smem + 5 * NBOXP * 4);
    __shared__ unsigned long long rmw[NWMAX], keepw[NWMAX];
    __shared__ int sCnt, sNV, sCorr, sProp;

    cg::grid_group grid = cg::this_grid();
    const int blk = blockIdx.x, tid = threadIdx.x;
    const int wv = tid >> 6, lane = tid & 63;
    const int b = blk & 7, g = blk >> 3;

    // ================= phase A: decode + compact + sort (blocks 0-7) ======
    if (blk < 8) {
        if (tid == 0) { sCnt = 0; sCorr = 0; sProp = 0; }
        if (blk == 0 && tid < 4) counters[tid] = 0;   // finisher state
        __syncthreads();
        const float* op = net + (size_t)b * (NA * 25 * NCELL);
        for (int n = tid; n < NBOX; n += 1024) {
            int a = n / NCELL;
            int r = n - a * NCELL;
            int y = r / 19;
            int x = r - y * 19;
            int base = a * 25 * NCELL + r;
            float t0 = op[base];
            float t1 = op[base + 1 * NCELL];
            float t2 = op[base + 2 * NCELL];
            float t3 = op[base + 3 * NCELL];
            float t4 = op[base + 4 * NCELL];
            float cx = (1.0f / (1.0f + expf(-t0)) + (float)x) / 19.0f;
            float cy = (1.0f / (1.0f + expf(-t1)) + (float)y) / 19.0f;
            float bw = expf(t2) * (d_anchw[a] / 19.0f);
            float bh = expf(t3) * (d_anchh[a] / 19.0f);
            float det = 1.0f / (1.0f + expf(-t4));
            sbox[n] = make_float4(cx, cy, bw, bh);
            bool valid = det > CONF_T;
            unsigned long long bm = __ballot(valid);
            int base0 = 0;
            if (lane == 0 && bm) base0 = atomicAdd(&sCnt, __popcll(bm));
            base0 = __shfl(base0, 0, 64);
            if (valid) {
                int pos = base0 + __popcll(bm & ((1ull << lane) - 1ull));
                // det desc; ties by original index asc (stable argsort match)
                skey[pos] = ((unsigned long long)(~__float_as_uint(det)) << 32) | (unsigned)n;
            }
        }
        if (wv == 2) {   // GT count via ballot (first row with cx==0)
            float cxv = (lane < TMAX) ? tgt[b * 250 + lane * 5 + 1] : 0.0f;
            unsigned long long bm = __ballot(cxv != 0.0f);
            unsigned long long inv = (~bm) & ((1ull << TMAX) - 1ull);
            if (lane == 0) sNV = inv ? (__ffsll((long long)inv) - 1) : TMAX;
        }
        __syncthreads();
        const int M = sCnt;
        if (tid == 0) Marr[b] = M;                   // for phase B
        int S = 64; while (S < M) S <<= 1;           // <= 2048
        for (int n = M + tid; n < S; n += 1024) skey[n] = ~0ull;
        __syncthreads();

        unsigned long long v[8];
        const int nt8 = S >> 3;
        const int base8 = tid << 3;
        auto cas = [&](int xx, int yy, bool up) {
            unsigned long long a = v[xx], c = v[yy];
            if ((a > c) == up) { v[xx] = c; v[yy] = a; }
        };
        if (tid < nt8) {
            #pragma unroll
            for (int p = 0; p < 8; ++p) v[p] = skey[base8 + p];
            cas(0,1,true); cas(2,3,false); cas(4,5,true); cas(6,7,false);
            cas(0,2,true); cas(1,3,true); cas(4,6,false); cas(5,7,false);
            cas(0,1,true); cas(2,3,true); cas(4,5,false); cas(6,7,false);
            bool u8 = ((base8 & 8) == 0);
            cas(0,4,u8); cas(1,5,u8); cas(2,6,u8); cas(3,7,u8);
            cas(0,2,u8); cas(1,3,u8); cas(4,6,u8); cas(5,7,u8);
            cas(0,1,u8); cas(2,3,u8); cas(4,5,u8); cas(6,7,u8);
            #pragma unroll
            for (int p = 0; p < 8; ++p) skey[base8 + p] = v[p];
        }
        __syncthreads();
        for (unsigned k = 16; k <= (unsigned)S; k <<= 1) {
            for (unsigned j = k >> 1; j >= 8; j >>= 1) {
                for (unsigned m = tid; m < (unsigned)(S >> 1); m += 1024) {
                    unsigned i = ((m & ~(j - 1)) << 1) | (m & (j - 1));
                    unsigned p = i | j;
                    bool up = ((i & k) == 0);
                    unsigned long long a = skey[i], c2 = skey[p];
                    if ((a > c2) == up) { skey[i] = c2; skey[p] = a; }
                }
                __syncthreads();
            }
            if (tid < nt8) {
                #pragma unroll
                for (int p = 0; p < 8; ++p) v[p] = skey[base8 + p];
                bool up = ((base8 & k) == 0);
                cas(0,4,up); cas(1,5,up); cas(2,6,up); cas(3,7,up);
                cas(0,2,up); cas(1,3,up); cas(4,6,up); cas(5,7,up);
                cas(0,1,up); cas(2,3,up); cas(4,5,up); cas(6,7,up);
                #pragma unroll
                for (int p = 0; p < 8; ++p) skey[base8 + p] = v[p];
            }
            __syncthreads();
        }

        // overlay: sorted SoA -> LDS (persists to phase C) + global (phase B)
        const int mceil = (M + 63) & ~63;
        const int p0 = tid, p1 = tid + 1024;
        unsigned long long k0 = (p0 < M) ? skey[p0] : 0ull;
        unsigned long long k1 = (p1 < M) ? skey[p1] : 0ull;
        float4 bx0 = (p0 < M) ? sbox[(unsigned)(k0 & 0xffffffffull)] : make_float4(0,0,0,0);
        float4 bx1 = (p1 < M) ? sbox[(unsigned)(k1 & 0xffffffffull)] : make_float4(0,0,0,0);
        __syncthreads();                 // all skey/sbox reads complete
        float* X1g = soa + 0 * SOA_ARR + b * SOA_STRIDE;
        float* Y1g = soa + 1 * SOA_ARR + b * SOA_STRIDE;
        float* X2g = soa + 2 * SOA_ARR + b * SOA_STRIDE;
        float* Y2g = soa + 3 * SOA_ARR + b * SOA_STRIDE;
        float* Wdg = soa + 4 * SOA_ARR + b * SOA_STRIDE;
        float* Hdg = soa + 5 * SOA_ARR + b * SOA_STRIDE;
        if (p0 < mceil) {
            float x1 = bx0.x - 0.5f * bx0.z, y1 = bx0.y - 0.5f * bx0.w;
            float x2 = bx0.x + 0.5f * bx0.z, y2 = bx0.y + 0.5f * bx0.w;
            X1s[p0] = x1; Y1s[p0] = y1; X2s[p0] = x2; Y2s[p0] = y2;
            Wss[p0] = bx0.z; Hss[p0] = bx0.w;
            X1g[p0] = x1; Y1g[p0] = y1; X2g[p0] = x2; Y2g[p0] = y2;
            Wdg[p0] = bx0.z; Hdg[p0] = bx0.w;
        }
        if (p1 < mceil) {
            float x1 = bx1.x - 0.5f * bx1.z, y1 = bx1.y - 0.5f * bx1.w;
            float x2 = bx1.x + 0.5f * bx1.z, y2 = bx1.y + 0.5f * bx1.w;
            X1s[p1] = x1; Y1s[p1] = y1; X2s[p1] = x2; Y2s[p1] = y2;
            Wss[p1] = bx1.z; Hss[p1] = bx1.w;
            X1g[p1] = x1; Y1g[p1] = y1; X2g[p1] = x2; Y2g[p1] = y2;
            Wdg[p1] = bx1.z; Hdg[p1] = bx1.w;
        }
    }
    __threadfence();       // release soa/Marr/counters device-wide
    grid.sync();

    // ================= phase B: chip-wide IoU mask (all blocks) ===========
    {
        const int Mb = Marr[b];
        const int i0 = g * 64 + wv * 4;         // 64 rows/block, 4/wave
        if (i0 < Mb) {
            const float* X1 = soa + 0 * SOA_ARR + b * SOA_STRIDE;
            const float* Y1 = soa + 1 * SOA_ARR + b * SOA_STRIDE;
            const float* X2 = soa + 2 * SOA_ARR + b * SOA_STRIDE;
            const float* Y2 = soa + 3 * SOA_ARR + b * SOA_STRIDE;
            const float* Wd = soa + 4 * SOA_ARR + b * SOA_STRIDE;
            const float* Hd = soa + 5 * SOA_ARR + b * SOA_STRIDE;
            const int nch = (Mb + 63) >> 6;
            const int w0  = i0 >> 6;            // triangular skip
            float ax1[4], ay1[4], ax2[4], ay2[4], aw[4], ah[4], aarea[4];
            #pragma unroll
            for (int r = 0; r < 4; ++r) {
                int ir = i0 + r; if (ir >= Mb) ir = Mb - 1;  // clamp; masked at store
                ax1[r] = X1[ir]; ay1[r] = Y1[ir];
                ax2[r] = X2[ir]; ay2[r] = Y2[ir];
                aw[r]  = Wd[ir]; ah[r]  = Hd[ir];
                aarea[r] = aw[r] * ah[r];
            }
            unsigned long long myw0 = 0, myw1 = 0, myw2 = 0, myw3 = 0;
            for (int w = w0; w < nch; ++w) {
                int j = (w << 6) + lane;        // < mceil (pad rows zeroed)
                float bx1 = X1[j], by1 = Y1[j];
                float bx2 = X2[j], by2 = Y2[j];
                float bw  = Wd[j], bh  = Hd[j];
                float barea = bw * bh;
                bool jok = (j < Mb);
                #pragma unroll
                for (int r = 0; r < 4; ++r) {
                    bool pred = false;
                    if (jok && j > i0 + r) {
                        float uw = fmaxf(ax2[r], bx2) - fminf(ax1[r], bx1);
                        float uh = fmaxf(ay2[r], by2) - fminf(ay1[r], by1);
                        float cw = aw[r] + bw - uw;
                        float ch = ah[r] + bh - uh;
                        if (cw > 0.0f && ch > 0.0f) {
                            float ca = cw * ch;
                            float ua = aarea[r] + barea - ca;
                            pred = ca > NMS_T * ua;      // iou > thresh
                        }
                    }
                    unsigned long long m = __ballot(pred);
                    if (w == lane) {
                        if      (r == 0) myw0 = m;
                        else if (r == 1) myw1 = m;
                        else if (r == 2) myw2 = m;
                        else             myw3 = m;
                    }
                }
            }
            if (lane >= w0 && lane < nch) {
                unsigned long long* dst = supT + ((size_t)b * 32 + lane) * ROWPAD;
                dst[i0] = myw0;
                if (i0 + 1 < Mb) dst[i0 + 1] = myw1;
                if (i0 + 2 < Mb) dst[i0 + 2] = myw2;
                if (i0 + 3 < Mb) dst[i0 + 3] = myw3;
            }
        }
    }
    __threadfence();       // release supT device-wide
    grid.sync();

    // ================= phase C: sweep + GT + finisher (blocks 0-7) ========
    if (blk < 8) {
        const int M = sCnt;                     // LDS persists from phase A
        const int nwa = (M + 63) >> 6;
        const unsigned long long* sb = supT + (size_t)b * 32 * ROWPAD;
        if (tid < NWMAX) { rmw[tid] = 0ull; keepw[tid] = 0ull; }

        // static word ownership: wave wv owns {wv, wv+15} (words 1..28)
        const int w1 = (wv >= 1) ? wv : -1;
        const int w2 = (wv >= 1 && wv + 15 <= 28) ? (wv + 15) : -1;
        unsigned long long cur1 = 0, cur2 = 0, diag = 0;
        if (wv == 0 && nwa > 0) diag = sb[lane];                        // tile0 diag
        if (w1 >= 1 && w1 < nwa) cur1 = sb[(size_t)w1 * ROWPAD + lane]; // tile0 col
        if (w2 >= 1 && w2 < nwa) cur2 = sb[(size_t)w2 * ROWPAD + lane];
        __syncthreads();   // rmw/keepw init visible

        for (int t = 0; t < nwa; ++t) {
            if (wv == 0) {
                // serial greedy sweep for tile t: readlane chain
                unsigned long long cur = rmw[t];
                int rem = M - (t << 6);
                unsigned long long vm = (rem >= 64) ? ~0ull : ((1ull << rem) - 1ull);
                unsigned long long live = vm & ~cur;
                while (live) {
                    int i = __ffsll((long long)live) - 1;       // uniform
                    unsigned long long w64 = rdlane64(diag, i);
                    cur |= w64;
                    live &= ~w64;
                    live &= ~(1ull << i);
                }
                unsigned long long kp = vm & ~cur;
                if (lane == 0) keepw[t] = kp;
                int tn = t + 1;
                if (tn < nwa) diag = sb[(size_t)tn * ROWPAD + (tn << 6) + lane];
            }
            barrier_lgkm();                        // keepw[t] visible
            {
                unsigned long long kmt = keepw[t];
                if (w1 > t && w1 < nwa) {
                    unsigned long long c = ((kmt >> lane) & 1ull) ? cur1 : 0ull;
                    c |= shflx64(c, 1);  c |= shflx64(c, 2);  c |= shflx64(c, 4);
                    c |= shflx64(c, 8);  c |= shflx64(c, 16); c |= shflx64(c, 32);
                    if (lane == 0) rmw[w1] |= c;   // word exclusively owned
                }
                if (w2 > t && w2 < nwa) {
                    unsigned long long c = ((kmt >> lane) & 1ull) ? cur2 : 0ull;
                    c |= shflx64(c, 1);  c |= shflx64(c, 2);  c |= shflx64(c, 4);
                    c |= shflx64(c, 8);  c |= shflx64(c, 16); c |= shflx64(c, 32);
                    if (lane == 0) rmw[w2] |= c;
                }
                // prefetch tile t+1 column — consumed after next sweep round
                if (w1 > t + 1 && w1 < nwa) cur1 = sb[(size_t)w1 * ROWPAD + ((t + 1) << 6) + lane];
                if (w2 > t + 1 && w2 < nwa) cur2 = sb[(size_t)w2 * ROWPAD + ((t + 1) << 6) + lane];
            }
            barrier_lgkm();                        // rmw final for sweep(t+1)
        }

        // proposals
        if (wv == 0) {
            unsigned long long kv = (lane < NWMAX) ? keepw[lane] : 0ull;
            int pc = __popcll(kv);
            for (int d = 32; d > 0; d >>= 1) pc += __shfl_down(pc, d, 64);
            if (lane == 0) sProp = pc;
        }

        // GT matching: 16 waves, branchless, LDS SoA; skip empty keep-words
        const int nv = sNV;
        for (int t = wv; t < nv; t += 16) {
            const float* gp = tgt + b * 250 + t * 5;
            float gcx = gp[1], gcy = gp[2], gw = gp[3], gh = gp[4];
            float gx1 = gcx - 0.5f * gw, gx2 = gcx + 0.5f * gw;
            float gy1 = gcy - 0.5f * gh, gy2 = gcy + 0.5f * gh;
            float garea = gw * gh;
            float best = 0.0f;
            for (int j0 = 0; j0 < M; j0 += 64) {
                unsigned long long kw = keepw[j0 >> 6];
                if (kw == 0ull) continue;          // wave-uniform skip
                int j = j0 + lane;
                bool ok = (j < M) && ((kw >> lane) & 1ull);
                int js = (j < NBOXP) ? j : (NBOXP - 1);
                float bw = Wss[js], bh = Hss[js];
                float uw = fmaxf(gx2, X2s[js]) - fminf(gx1, X1s[js]);
                float uh = fmaxf(gy2, Y2s[js]) - fminf(gy1, Y1s[js]);
                float cww = gw + bw - uw, chh = gh + bh - uh;
                float ca = (cww > 0.0f && chh > 0.0f) ? cww * chh : 0.0f;
                float ua = garea + bw * bh - ca;
                float iou = ca / ua;
                best = fmaxf(best, ok ? iou : 0.0f);
            }
            for (int d = 32; d > 0; d >>= 1) best = fmaxf(best, __shfl_down(best, d, 64));
            if (lane == 0 && best > IOU_T) atomicAdd(&sCorr, 1);
        }
        barrier_lgkm();    // sProp/sCorr visible

        // finisher (done==7 protocol, measured-correct in prior passing runs)
        if (tid == 0) {
            atomicAdd(counters + 0, sProp);
            atomicAdd(counters + 1, sCorr);
            atomicAdd(counters + 2, sNV);
            __threadfence();
            int done = atomicAdd(counters + 3, 1);
            if (done == 7) {
                float prop  = (float)atomicAdd(counters + 0, 0);
                float corr  = (float)atomicAdd(counters + 1, 0);
                float total = (float)atomicAdd(counters + 2, 0);
                float prec = corr / (prop + 1e-6f);
                float rec  = corr / (total + 1e-6f);
                float fs   = 2.0f * prec * rec / (prec + rec + 1e-6f);
                out[0] = total;
                out[1] = prop;
                out[2] = corr;
                out[3] = prec;
                out[4] = rec;
                out[5] = fs;
            }
        }
    }
}

extern "C" void kernel_launch(void* const* d_in, const int* in_sizes, int n_in,
                              void* d_out, int out_size, void* d_ws, size_t ws_size,
                              hipStream_t stream) {
    const float* net = (const float*)d_in[0];   // [8,125,19,19] f32
    const float* tgt = (const float*)d_in[1];   // [8,250] f32
    char* ws = (char*)d_ws;
    int* counters = (int*)(ws + WS_COUNT);
    int* Marr     = (int*)(ws + WS_M);
    float* soa    = (float*)(ws + WS_SOA);
    unsigned long long* supT = (unsigned long long*)(ws + WS_SUP);
    float* out = (float*)d_out;

    void* args[] = { (void*)&net, (void*)&tgt, (void*)&soa, (void*)&supT,
                     (void*)&Marr, (void*)&counters, (void*)&out };
    hipLaunchCooperativeKernel(k_all, dim3(NBLK), dim3(1024), args, 0, stream);
}

// Round 12
// 130.035 us; speedup vs baseline: 2.4044x; 2.4044x over previous
//
#include <hip/hip_runtime.h>

namespace {
constexpr int NA    = 5;
constexpr int NCELL = 361;            // 19*19
constexpr int NBOX  = 1805;           // NA * NCELL
constexpr int NBOXP = 1856;           // NBOX rounded up to 64
constexpr int NT1   = 1024;           // K1 threads (16 waves: hide sort barriers)
constexpr int TMAX  = 50;
constexpr float CONF_T = 0.5f;
constexpr float NMS_T  = 0.45f;
constexpr float IOU_T  = 0.5f;
constexpr int NWMAX   = 32;           // keep/remove words (29 needed)
constexpr int ROWPAD  = 1856;         // supT padded row dim
constexpr int SOA_STRIDE = NBOXP;
constexpr int SOA_ARR    = 8 * SOA_STRIDE;
// ws layout (bytes)
constexpr size_t WS_COUNT = 0;        // 4 ints: prop, corr, total, done
constexpr size_t WS_M     = 64;       // 8 ints
constexpr size_t WS_SOA   = 256;      // 6 * SOA_ARR floats = 356,352 B
constexpr size_t WS_SUP   = 360448;   // 8 * 32 * ROWPAD * 8 = 3,801,088 B
}

__device__ __constant__ float d_anchw[NA] = {1.3221f, 3.19275f, 5.05587f, 9.47112f, 11.2364f};
__device__ __constant__ float d_anchh[NA] = {1.73145f, 4.00944f, 8.09892f, 4.84053f, 10.0071f};

__device__ inline unsigned long long shflx64(unsigned long long v, int m) {
    int lo = __shfl_xor((int)(unsigned)(v & 0xffffffffull), m, 64);
    int hi = __shfl_xor((int)(unsigned)(v >> 32), m, 64);
    return ((unsigned long long)(unsigned)hi << 32) | (unsigned)lo;
}
// uniform-index 64-bit readlane: ~3 cyc vs ~60-80 cyc for ds_bpermute shuffles
__device__ inline unsigned long long rdlane64(unsigned long long v, int l) {
    unsigned lo = (unsigned)__builtin_amdgcn_readlane((int)(unsigned)(v & 0xffffffffull), l);
    unsigned hi = (unsigned)__builtin_amdgcn_readlane((int)(unsigned)(v >> 32), l);
    return ((unsigned long long)hi << 32) | lo;
}
// Barrier that waits ONLY on LDS (lgkmcnt(0)); global prefetch loads stay in
// flight across the barrier. 0xC07F = vmcnt(63)|expcnt(7)|lgkmcnt(0).
__device__ inline void barrier_lgkm() {
    __asm__ volatile("" ::: "memory");
    __builtin_amdgcn_s_waitcnt(0xC07F);
    __builtin_amdgcn_s_barrier();
    __asm__ volatile("" ::: "memory");
}

// ---- K1: decode + conf-compaction + bitonic sort (S = pow2 >= M) + sorted
// zero-padded SoA to global. 1024 threads: 16 waves hide the ~36 barrier
// phases of the sort and cut decode to 2 iterations. ----
__global__ __launch_bounds__(NT1, 1) void k_decode_sort(
    const float* __restrict__ net, float* __restrict__ soa,
    int* __restrict__ Marr, int* __restrict__ counters)
{
    __shared__ unsigned long long skey[2048];    // 16 KB
    __shared__ float4 sbox[NBOX];                // 28.9 KB
    __shared__ int sCnt;
    const int b = blockIdx.x, tid = threadIdx.x, lane = tid & 63;
    const float* op = net + (size_t)b * (NA * 25 * NCELL);
    if (tid == 0) sCnt = 0;
    if (b == 0 && tid < 4) counters[tid] = 0;    // K3 finisher state (stream-ordered)
    __syncthreads();

    // decode + compaction: only det>CONF_T enter the sort (invalid boxes never
    // suppress, are never counted as proposals, never match GT)
    for (int n = tid; n < NBOX; n += NT1) {
        int a = n / NCELL;
        int r = n - a * NCELL;
        int y = r / 19;
        int x = r - y * 19;
        int base = a * 25 * NCELL + r;
        float t0 = op[base];
        float t1 = op[base + 1 * NCELL];
        float t2 = op[base + 2 * NCELL];
        float t3 = op[base + 3 * NCELL];
        float t4 = op[base + 4 * NCELL];
        float cx = (1.0f / (1.0f + expf(-t0)) + (float)x) / 19.0f;
        float cy = (1.0f / (1.0f + expf(-t1)) + (float)y) / 19.0f;
        float bw = expf(t2) * (d_anchw[a] / 19.0f);
        float bh = expf(t3) * (d_anchh[a] / 19.0f);
        float det = 1.0f / (1.0f + expf(-t4));
        sbox[n] = make_float4(cx, cy, bw, bh);
        bool valid = det > CONF_T;
        unsigned long long bm = __ballot(valid);
        int base0 = 0;
        if (lane == 0 && bm) base0 = atomicAdd(&sCnt, __popcll(bm));
        base0 = __shfl(base0, 0, 64);
        if (valid) {
            int pos = base0 + __popcll(bm & ((1ull << lane) - 1ull));
            // det desc; ties broken by original index n asc (matches stable argsort)
            skey[pos] = ((unsigned long long)(~__float_as_uint(det)) << 32) | (unsigned)n;
        }
    }
    __syncthreads();
    const int M = sCnt;
    int S = 64; while (S < M) S <<= 1;            // <= 2048
    for (int n = M + tid; n < S; n += NT1) skey[n] = ~0ull;
    __syncthreads();

    // bitonic sort of S keys; 8-key register blocks handle j<=4 phases
    unsigned long long v[8];
    const int nt8 = S >> 3;                       // threads doing 8-key blocks
    const int base8 = tid << 3;
    auto cas = [&](int xx, int yy, bool up) {
        unsigned long long a = v[xx], c = v[yy];
        if ((a > c) == up) { v[xx] = c; v[yy] = a; }
    };
    if (tid < nt8) {
        #pragma unroll
        for (int p = 0; p < 8; ++p) v[p] = skey[base8 + p];
        cas(0,1,true); cas(2,3,false); cas(4,5,true); cas(6,7,false);
        cas(0,2,true); cas(1,3,true); cas(4,6,false); cas(5,7,false);
        cas(0,1,true); cas(2,3,true); cas(4,5,false); cas(6,7,false);
        bool u8 = ((base8 & 8) == 0);
        cas(0,4,u8); cas(1,5,u8); cas(2,6,u8); cas(3,7,u8);
        cas(0,2,u8); cas(1,3,u8); cas(4,6,u8); cas(5,7,u8);
        cas(0,1,u8); cas(2,3,u8); cas(4,5,u8); cas(6,7,u8);
        #pragma unroll
        for (int p = 0; p < 8; ++p) skey[base8 + p] = v[p];
    }
    __syncthreads();
    for (unsigned k = 16; k <= (unsigned)S; k <<= 1) {
        for (unsigned j = k >> 1; j >= 8; j >>= 1) {
            for (unsigned m = tid; m < (unsigned)(S >> 1); m += NT1) {
                unsigned i = ((m & ~(j - 1)) << 1) | (m & (j - 1));
                unsigned p = i | j;
                bool up = ((i & k) == 0);
                unsigned long long a = skey[i], c2 = skey[p];
                if ((a > c2) == up) { skey[i] = c2; skey[p] = a; }
            }
            __syncthreads();
        }
        if (tid < nt8) {
            #pragma unroll
            for (int p = 0; p < 8; ++p) v[p] = skey[base8 + p];
            bool up = ((base8 & k) == 0);
            cas(0,4,up); cas(1,5,up); cas(2,6,up); cas(3,7,up);
            cas(0,2,up); cas(1,3,up); cas(4,6,up); cas(5,7,up);
            cas(0,1,up); cas(2,3,up); cas(4,5,up); cas(6,7,up);
            #pragma unroll
            for (int p = 0; p < 8; ++p) skey[base8 + p] = v[p];
        }
        __syncthreads();
    }

    // sorted SoA to global, zero-padded to mceil (K2/K3 read pad rows freely)
    float* X1 = soa + 0 * SOA_ARR + b * SOA_STRIDE;
    float* Y1 = soa + 1 * SOA_ARR + b * SOA_STRIDE;
    float* X2 = soa + 2 * SOA_ARR + b * SOA_STRIDE;
    float* Y2 = soa + 3 * SOA_ARR + b * SOA_STRIDE;
    float* Wd = soa + 4 * SOA_ARR + b * SOA_STRIDE;
    float* Hd = soa + 5 * SOA_ARR + b * SOA_STRIDE;
    const int mceil = (M + 63) & ~63;
    for (int p = tid; p < mceil; p += NT1) {
        float4 bx = make_float4(0.f, 0.f, 0.f, 0.f);
        if (p < M) bx = sbox[(unsigned)(skey[p] & 0xffffffffull)];
        X1[p] = bx.x - 0.5f * bx.z;
        Y1[p] = bx.y - 0.5f * bx.w;
        X2[p] = bx.x + 0.5f * bx.z;
        Y2[p] = bx.y + 0.5f * bx.w;
        Wd[p] = bx.z;
        Hd[p] = bx.w;
    }
    if (tid == 0) Marr[b] = M;
}

// ---- K2: suppression words, chip-wide. 16 rows/block (4 rows/wave, column
// data loaded once per wave, reused 4x). Triangular skip: word w < row>>6 is
// never read by k_sweep -> start at w0 and skip those loads/ballots/stores. ----
__global__ __launch_bounds__(256) void k_iou_maskT(
    const float* __restrict__ soa, const int* __restrict__ Marr,
    unsigned long long* __restrict__ supT)
{
    const int blk  = blockIdx.x;
    const int b    = blk & 7;             // batch -> stable XCD under round-robin
    const int g    = blk >> 3;            // 16-row group
    const int wv   = threadIdx.x >> 6;
    const int lane = threadIdx.x & 63;
    const int M = Marr[b];
    const int i0 = g * 16 + wv * 4;       // this wave's first row
    if (i0 >= M) return;                  // per-wave exit (no barriers below)
    const float* X1 = soa + 0 * SOA_ARR + b * SOA_STRIDE;
    const float* Y1 = soa + 1 * SOA_ARR + b * SOA_STRIDE;
    const float* X2 = soa + 2 * SOA_ARR + b * SOA_STRIDE;
    const float* Y2 = soa + 3 * SOA_ARR + b * SOA_STRIDE;
    const float* Wd = soa + 4 * SOA_ARR + b * SOA_STRIDE;
    const float* Hd = soa + 5 * SOA_ARR + b * SOA_STRIDE;
    const int nch = (M + 63) >> 6;
    const int w0  = i0 >> 6;              // rows i0..i0+3 share i>>6 (4 | 64)

    float ax1[4], ay1[4], ax2[4], ay2[4], aw[4], ah[4], aarea[4];
    #pragma unroll
    for (int r = 0; r < 4; ++r) {
        int ir = i0 + r; if (ir >= M) ir = M - 1;   // clamp; masked at store
        ax1[r] = X1[ir]; ay1[r] = Y1[ir];
        ax2[r] = X2[ir]; ay2[r] = Y2[ir];
        aw[r]  = Wd[ir]; ah[r]  = Hd[ir];
        aarea[r] = aw[r] * ah[r];
    }
    unsigned long long myw0 = 0, myw1 = 0, myw2 = 0, myw3 = 0;
    for (int w = w0; w < nch; ++w) {
        int j = (w << 6) + lane;          // < mceil always (pad rows are zero)
        float bx1 = X1[j], by1 = Y1[j];
        float bx2 = X2[j], by2 = Y2[j];
        float bw  = Wd[j], bh  = Hd[j];
        float barea = bw * bh;
        bool jok = (j < M);
        #pragma unroll
        for (int r = 0; r < 4; ++r) {
            bool pred = false;
            if (jok && j > i0 + r) {
                float uw = fmaxf(ax2[r], bx2) - fminf(ax1[r], bx1);
                float uh = fmaxf(ay2[r], by2) - fminf(ay1[r], by1);
                float cw = aw[r] + bw - uw;
                float ch = ah[r] + bh - uh;
                if (cw > 0.0f && ch > 0.0f) {
                    float ca = cw * ch;
                    float ua = aarea[r] + barea - ca;
                    pred = ca > NMS_T * ua;          // iou > thresh
                }
            }
            unsigned long long m = __ballot(pred);
            if (w == lane) {
                if      (r == 0) myw0 = m;
                else if (r == 1) myw1 = m;
                else if (r == 2) myw2 = m;
                else             myw3 = m;
            }
        }
    }
    if (lane >= w0 && lane < nch) {
        unsigned long long* dst = supT + ((size_t)b * 32 + lane) * ROWPAD;
        dst[i0] = myw0;
        if (i0 + 1 < M) dst[i0 + 1] = myw1;
        if (i0 + 2 < M) dst[i0 + 2] = myw2;
        if (i0 + 3 < M) dst[i0 + 3] = myw3;
    }
}

// ---- K3: 16-wave greedy sweep, Round-6 two-barrier form (measured 48.8us);
// lgkm-only barriers keep prefetches in flight. Wave 0: readlane serial chain.
// Waves 1-15: owned future-words with cross-barrier prefetch. GT match from
// LDS SoA. Finisher merged (done==7 protocol). ----
__global__ __launch_bounds__(1024, 1) void k_sweep(
    const float* __restrict__ soa, const float* __restrict__ tgt,
    const int* __restrict__ Marr, const unsigned long long* __restrict__ supT,
    int* __restrict__ counters, float* __restrict__ out)
{
    __shared__ float X1s[NBOXP], Y1s[NBOXP], X2s[NBOXP], Y2s[NBOXP];
    __shared__ float Wss[NBOXP], Hss[NBOXP];             // 44.5 KB
    __shared__ unsigned long long rmw[NWMAX], keepw[NWMAX];
    __shared__ int sNV, sCorr, sProp;
    const int b = blockIdx.x, tid = threadIdx.x;
    const int wv = tid >> 6, lane = tid & 63;
    const int M = Marr[b];
    const int nwa = (M + 63) >> 6;
    const unsigned long long* sb = supT + (size_t)b * 32 * ROWPAD;

    if (tid < NWMAX) { rmw[tid] = 0ull; keepw[tid] = 0ull; }
    if (tid == 0) { sCorr = 0; sProp = 0; }

    // stage sorted SoA into LDS (only rows the sweep/GT can touch)
    {
        int mceil = (M + 63) & ~63;
        const float* X1 = soa + 0 * SOA_ARR + b * SOA_STRIDE;
        const float* Y1 = soa + 1 * SOA_ARR + b * SOA_STRIDE;
        const float* X2 = soa + 2 * SOA_ARR + b * SOA_STRIDE;
        const float* Y2 = soa + 3 * SOA_ARR + b * SOA_STRIDE;
        const float* Wd = soa + 4 * SOA_ARR + b * SOA_STRIDE;
        const float* Hd = soa + 5 * SOA_ARR + b * SOA_STRIDE;
        for (int p = tid; p < mceil; p += 1024) {
            X1s[p] = X1[p]; Y1s[p] = Y1[p];
            X2s[p] = X2[p]; Y2s[p] = Y2[p];
            Wss[p] = Wd[p]; Hss[p] = Hd[p];
        }
    }
    if (wv == 2) {       // GT count via ballot (first row with cx==0)
        float cxv = (lane < TMAX) ? tgt[b * 250 + lane * 5 + 1] : 0.0f;
        unsigned long long bm = __ballot(cxv != 0.0f);
        unsigned long long inv = (~bm) & ((1ull << TMAX) - 1ull);
        if (lane == 0) sNV = inv ? (__ffsll((long long)inv) - 1) : TMAX;
    }

    // static word ownership: wave wv owns {wv, wv+15} (covers words 1..28)
    const int w1 = (wv >= 1) ? wv : -1;
    const int w2 = (wv >= 1 && wv + 15 <= 28) ? (wv + 15) : -1;
    unsigned long long cur1 = 0, cur2 = 0, diag = 0;
    if (wv == 0 && nwa > 0) diag = sb[lane];                        // tile0 diag
    if (w1 >= 1 && w1 < nwa) cur1 = sb[(size_t)w1 * ROWPAD + lane]; // tile0 col
    if (w2 >= 1 && w2 < nwa) cur2 = sb[(size_t)w2 * ROWPAD + lane];
    __syncthreads();     // staging + keepw/rmw init visible

    for (int t = 0; t < nwa; ++t) {
        if (wv == 0) {
            // serial greedy sweep for tile t: readlane chain
            unsigned long long cur = rmw[t];
            int rem = M - (t << 6);
            unsigned long long vm = (rem >= 64) ? ~0ull : ((1ull << rem) - 1ull);
            unsigned long long live = vm & ~cur;
            while (live) {
                int i = __ffsll((long long)live) - 1;       // uniform
                unsigned long long w64 = rdlane64(diag, i);
                cur |= w64;
                live &= ~w64;
                live &= ~(1ull << i);
            }
            unsigned long long kp = vm & ~cur;
            if (lane == 0) keepw[t] = kp;
            int tn = t + 1;
            if (tn < nwa) diag = sb[(size_t)tn * ROWPAD + (tn << 6) + lane];
        }
        barrier_lgkm();                        // keepw[t] visible
        {
            unsigned long long kmt = keepw[t];
            if (w1 > t && w1 < nwa) {
                unsigned long long c = ((kmt >> lane) & 1ull) ? cur1 : 0ull;
                c |= shflx64(c, 1);  c |= shflx64(c, 2);  c |= shflx64(c, 4);
                c |= shflx64(c, 8);  c |= shflx64(c, 16); c |= shflx64(c, 32);
                if (lane == 0) rmw[w1] |= c;   // word exclusively owned
            }
            if (w2 > t && w2 < nwa) {
                unsigned long long c = ((kmt >> lane) & 1ull) ? cur2 : 0ull;
                c |= shflx64(c, 1);  c |= shflx64(c, 2);  c |= shflx64(c, 4);
                c |= shflx64(c, 8);  c |= shflx64(c, 16); c |= shflx64(c, 32);
                if (lane == 0) rmw[w2] |= c;
            }
            // prefetch tile t+1 column — consumed after next sweep round
            if (w1 > t + 1 && w1 < nwa) cur1 = sb[(size_t)w1 * ROWPAD + ((t + 1) << 6) + lane];
            if (w2 > t + 1 && w2 < nwa) cur2 = sb[(size_t)w2 * ROWPAD + ((t + 1) << 6) + lane];
        }
        barrier_lgkm();                        // rmw final for sweep(t+1)
    }

    // proposals
    if (wv == 0) {
        unsigned long long kv = (lane < NWMAX) ? keepw[lane] : 0ull;
        int pc = __popcll(kv);
        for (int d = 32; d > 0; d >>= 1) pc += __shfl_down(pc, d, 64);
        if (lane == 0) sProp = pc;
    }

    // GT matching: 16 waves, branchless, LDS SoA; skip empty keep-words
    const int nv = sNV;
    for (int t = wv; t < nv; t += 16) {
        const float* g = tgt + b * 250 + t * 5;
        float gcx = g[1], gcy = g[2], gw = g[3], gh = g[4];
        float gx1 = gcx - 0.5f * gw, gx2 = gcx + 0.5f * gw;
        float gy1 = gcy - 0.5f * gh, gy2 = gcy + 0.5f * gh;
        float garea = gw * gh;
        float best = 0.0f;
        for (int j0 = 0; j0 < M; j0 += 64) {
            unsigned long long kw = keepw[j0 >> 6];
            if (kw == 0ull) continue;          // wave-uniform skip
            int j = j0 + lane;
            bool ok = (j < M) && ((kw >> lane) & 1ull);
            int js = (j < NBOXP) ? j : (NBOXP - 1);
            float bw = Wss[js], bh = Hss[js];
            float uw = fmaxf(gx2, X2s[js]) - fminf(gx1, X1s[js]);
            float uh = fmaxf(gy2, Y2s[js]) - fminf(gy1, Y1s[js]);
            float cww = gw + bw - uw, chh = gh + bh - uh;
            float ca = (cww > 0.0f && chh > 0.0f) ? cww * chh : 0.0f;
            float ua = garea + bw * bh - ca;
            float iou = ca / ua;
            best = fmaxf(best, ok ? iou : 0.0f);
        }
        for (int d = 32; d > 0; d >>= 1) best = fmaxf(best, __shfl_down(best, d, 64));
        if (lane == 0 && best > IOU_T) atomicAdd(&sCorr, 1);
    }
    barrier_lgkm();     // sProp/sCorr visible to tid 0

    // in-kernel finisher (protocol measured-correct in prior passing runs)
    if (tid == 0) {
        atomicAdd(counters + 0, sProp);
        atomicAdd(counters + 1, sCorr);
        atomicAdd(counters + 2, sNV);
        __threadfence();
        int done = atomicAdd(counters + 3, 1);
        if (done == 7) {
            float prop  = (float)atomicAdd(counters + 0, 0);
            float corr  = (float)atomicAdd(counters + 1, 0);
            float total = (float)atomicAdd(counters + 2, 0);
            float prec = corr / (prop + 1e-6f);
            float rec  = corr / (total + 1e-6f);
            float fs   = 2.0f * prec * rec / (prec + rec + 1e-6f);
            out[0] = total;
            out[1] = prop;
            out[2] = corr;
            out[3] = prec;
            out[4] = rec;
            out[5] = fs;
        }
    }
}

extern "C" void kernel_launch(void* const* d_in, const int* in_sizes, int n_in,
                              void* d_out, int out_size, void* d_ws, size_t ws_size,
                              hipStream_t stream) {
    const float* net = (const float*)d_in[0];   // [8,125,19,19] f32
    const float* tgt = (const float*)d_in[1];   // [8,250] f32
    char* ws = (char*)d_ws;
    int* counters = (int*)(ws + WS_COUNT);
    int* Marr     = (int*)(ws + WS_M);
    float* soa    = (float*)(ws + WS_SOA);
    unsigned long long* supT = (unsigned long long*)(ws + WS_SUP);

    k_decode_sort<<<8, NT1, 0, stream>>>(net, soa, Marr, counters);
    int rowblocks = (NBOX + 15) / 16;            // 113 groups of 16 rows
    k_iou_maskT<<<rowblocks * 8, 256, 0, stream>>>(soa, Marr, supT);
    k_sweep<<<8, 1024, 0, stream>>>(soa, tgt, Marr, supT, counters, (float*)d_out);
}

// Round 17
// 128.670 us; speedup vs baseline: 2.4299x; 1.0106x over previous
//
#include <hip/hip_runtime.h>

namespace {
constexpr int NA    = 5;
constexpr int NCELL = 361;            // 19*19
constexpr int NBOX  = 1805;           // NA * NCELL
constexpr int NBOXP = 1856;           // NBOX rounded up to 64
constexpr int NT1   = 1024;           // K1 threads (16 waves: hide sort barriers)
constexpr int TMAX  = 50;
constexpr float CONF_T = 0.5f;
constexpr float NMS_T  = 0.45f;
constexpr float IOU_T  = 0.5f;
constexpr int NW     = 29;            // max words (ceil(1805/64))
constexpr int NWMAX  = 32;            // rmw/keepw array size
constexpr int SOA_STRIDE = NBOXP;
constexpr int SOA_ARR    = 8 * SOA_STRIDE;
// packed triangular supT: word w holds rows [0, (w+1)*64) -> per-batch words
constexpr int TRIW = 64 * (NW * (NW + 1) / 2);   // 27840 words = 222,720 B
// ws layout (bytes)
constexpr size_t WS_COUNT = 0;        // 4 ints: prop, corr, total, done
constexpr size_t WS_M     = 64;       // 8 ints
constexpr size_t WS_SOA   = 256;      // 6 * SOA_ARR floats = 356,352 B
constexpr size_t WS_SUP   = 360448;   // 8 * TRIW * 8 = 1,781,760 B (was 3.8 MB)
__device__ inline size_t tri_off(int w) { return (size_t)32 * w * (w + 1); } // 64*w(w+1)/2
}

__device__ __constant__ float d_anchw[NA] = {1.3221f, 3.19275f, 5.05587f, 9.47112f, 11.2364f};
__device__ __constant__ float d_anchh[NA] = {1.73145f, 4.00944f, 8.09892f, 4.84053f, 10.0071f};

// uniform-index 64-bit readlane: ~3 cyc vs ~60-80 cyc for ds_bpermute shuffles
__device__ inline unsigned long long rdlane64(unsigned long long v, int l) {
    unsigned lo = (unsigned)__builtin_amdgcn_readlane((int)(unsigned)(v & 0xffffffffull), l);
    unsigned hi = (unsigned)__builtin_amdgcn_readlane((int)(unsigned)(v >> 32), l);
    return ((unsigned long long)hi << 32) | lo;
}
// Barrier that waits ONLY on LDS (lgkmcnt(0)); global prefetch loads stay in
// flight across the barrier. 0xC07F = vmcnt(63)|expcnt(7)|lgkmcnt(0).
__device__ inline void barrier_lgkm() {
    __asm__ volatile("" ::: "memory");
    __builtin_amdgcn_s_waitcnt(0xC07F);
    __builtin_amdgcn_s_barrier();
    __asm__ volatile("" ::: "memory");
}

// ---- K1: decode + conf-compaction + bitonic sort (S = pow2 >= M) + sorted
// zero-padded SoA to global. 1024 threads (16 waves). ----
__global__ __launch_bounds__(NT1, 1) void k_decode_sort(
    const float* __restrict__ net, float* __restrict__ soa,
    int* __restrict__ Marr, int* __restrict__ counters)
{
    __shared__ unsigned long long skey[2048];    // 16 KB
    __shared__ float4 sbox[NBOX];                // 28.9 KB
    __shared__ int sCnt;
    const int b = blockIdx.x, tid = threadIdx.x, lane = tid & 63;
    const float* op = net + (size_t)b * (NA * 25 * NCELL);
    if (tid == 0) sCnt = 0;
    if (b == 0 && tid < 4) counters[tid] = 0;    // K3 finisher state (stream-ordered)
    __syncthreads();

    // decode + compaction: only det>CONF_T enter the sort (invalid boxes never
    // suppress, are never counted as proposals, never match GT)
    for (int n = tid; n < NBOX; n += NT1) {
        int a = n / NCELL;
        int r = n - a * NCELL;
        int y = r / 19;
        int x = r - y * 19;
        int base = a * 25 * NCELL + r;
        float t0 = op[base];
        float t1 = op[base + 1 * NCELL];
        float t2 = op[base + 2 * NCELL];
        float t3 = op[base + 3 * NCELL];
        float t4 = op[base + 4 * NCELL];
        float cx = (1.0f / (1.0f + expf(-t0)) + (float)x) / 19.0f;
        float cy = (1.0f / (1.0f + expf(-t1)) + (float)y) / 19.0f;
        float bw = expf(t2) * (d_anchw[a] / 19.0f);
        float bh = expf(t3) * (d_anchh[a] / 19.0f);
        float det = 1.0f / (1.0f + expf(-t4));
        sbox[n] = make_float4(cx, cy, bw, bh);
        bool valid = det > CONF_T;
        unsigned long long bm = __ballot(valid);
        int base0 = 0;
        if (lane == 0 && bm) base0 = atomicAdd(&sCnt, __popcll(bm));
        base0 = __shfl(base0, 0, 64);
        if (valid) {
            int pos = base0 + __popcll(bm & ((1ull << lane) - 1ull));
            // det desc; ties broken by original index n asc (matches stable argsort)
            skey[pos] = ((unsigned long long)(~__float_as_uint(det)) << 32) | (unsigned)n;
        }
    }
    __syncthreads();
    const int M = sCnt;
    int S = 64; while (S < M) S <<= 1;            // <= 2048
    for (int n = M + tid; n < S; n += NT1) skey[n] = ~0ull;
    __syncthreads();

    // bitonic sort of S keys; 8-key register blocks handle j<=4 phases
    unsigned long long v[8];
    const int nt8 = S >> 3;                       // threads doing 8-key blocks
    const int base8 = tid << 3;
    auto cas = [&](int xx, int yy, bool up) {
        unsigned long long a = v[xx], c = v[yy];
        if ((a > c) == up) { v[xx] = c; v[yy] = a; }
    };
    if (tid < nt8) {
        #pragma unroll
        for (int p = 0; p < 8; ++p) v[p] = skey[base8 + p];
        cas(0,1,true); cas(2,3,false); cas(4,5,true); cas(6,7,false);
        cas(0,2,true); cas(1,3,true); cas(4,6,false); cas(5,7,false);
        cas(0,1,true); cas(2,3,true); cas(4,5,false); cas(6,7,false);
        bool u8 = ((base8 & 8) == 0);
        cas(0,4,u8); cas(1,5,u8); cas(2,6,u8); cas(3,7,u8);
        cas(0,2,u8); cas(1,3,u8); cas(4,6,u8); cas(5,7,u8);
        cas(0,1,u8); cas(2,3,u8); cas(4,5,u8); cas(6,7,u8);
        #pragma unroll
        for (int p = 0; p < 8; ++p) skey[base8 + p] = v[p];
    }
    __syncthreads();
    for (unsigned k = 16; k <= (unsigned)S; k <<= 1) {
        for (unsigned j = k >> 1; j >= 8; j >>= 1) {
            for (unsigned m = tid; m < (unsigned)(S >> 1); m += NT1) {
                unsigned i = ((m & ~(j - 1)) << 1) | (m & (j - 1));
                unsigned p = i | j;
                bool up = ((i & k) == 0);
                unsigned long long a = skey[i], c2 = skey[p];
                if ((a > c2) == up) { skey[i] = c2; skey[p] = a; }
            }
            __syncthreads();
        }
        if (tid < nt8) {
            #pragma unroll
            for (int p = 0; p < 8; ++p) v[p] = skey[base8 + p];
            bool up = ((base8 & k) == 0);
            cas(0,4,up); cas(1,5,up); cas(2,6,up); cas(3,7,up);
            cas(0,2,up); cas(1,3,up); cas(4,6,up); cas(5,7,up);
            cas(0,1,up); cas(2,3,up); cas(4,5,up); cas(6,7,up);
            #pragma unroll
            for (int p = 0; p < 8; ++p) skey[base8 + p] = v[p];
        }
        __syncthreads();
    }

    // sorted SoA to global, zero-padded to mceil (K2/K3 read pad rows freely)
    float* X1 = soa + 0 * SOA_ARR + b * SOA_STRIDE;
    float* Y1 = soa + 1 * SOA_ARR + b * SOA_STRIDE;
    float* X2 = soa + 2 * SOA_ARR + b * SOA_STRIDE;
    float* Y2 = soa + 3 * SOA_ARR + b * SOA_STRIDE;
    float* Wd = soa + 4 * SOA_ARR + b * SOA_STRIDE;
    float* Hd = soa + 5 * SOA_ARR + b * SOA_STRIDE;
    const int mceil = (M + 63) & ~63;
    for (int p = tid; p < mceil; p += NT1) {
        float4 bx = make_float4(0.f, 0.f, 0.f, 0.f);
        if (p < M) bx = sbox[(unsigned)(skey[p] & 0xffffffffull)];
        X1[p] = bx.x - 0.5f * bx.z;
        Y1[p] = bx.y - 0.5f * bx.w;
        X2[p] = bx.x + 0.5f * bx.z;
        Y2[p] = bx.y + 0.5f * bx.w;
        Wd[p] = bx.z;
        Hd[p] = bx.w;
    }
    if (tid == 0) Marr[b] = M;
}

// ---- K2: suppression words, chip-wide, packed-triangular store. 16 rows/
// block (4 rows/wave, column data loaded once per wave, reused 4x).
// Triangular skip: word w < row>>6 is never read by k_sweep. ----
__global__ __launch_bounds__(256) void k_iou_maskT(
    const float* __restrict__ soa, const int* __restrict__ Marr,
    unsigned long long* __restrict__ supT)
{
    const int blk  = blockIdx.x;
    const int b    = blk & 7;             // batch -> stable XCD under round-robin
    const int g    = blk >> 3;            // 16-row group
    const int wv   = threadIdx.x >> 6;
    const int lane = threadIdx.x & 63;
    const int M = Marr[b];
    const int i0 = g * 16 + wv * 4;       // this wave's first row
    if (i0 >= M) return;                  // per-wave exit (no barriers below)
    const float* X1 = soa + 0 * SOA_ARR + b * SOA_STRIDE;
    const float* Y1 = soa + 1 * SOA_ARR + b * SOA_STRIDE;
    const float* X2 = soa + 2 * SOA_ARR + b * SOA_STRIDE;
    const float* Y2 = soa + 3 * SOA_ARR + b * SOA_STRIDE;
    const float* Wd = soa + 4 * SOA_ARR + b * SOA_STRIDE;
    const float* Hd = soa + 5 * SOA_ARR + b * SOA_STRIDE;
    const int nch = (M + 63) >> 6;
    const int w0  = i0 >> 6;              // rows i0..i0+3 share i>>6 (4 | 64)

    float ax1[4], ay1[4], ax2[4], ay2[4], aw[4], ah[4], aarea[4];
    #pragma unroll
    for (int r = 0; r < 4; ++r) {
        int ir = i0 + r; if (ir >= M) ir = M - 1;   // clamp; masked at store
        ax1[r] = X1[ir]; ay1[r] = Y1[ir];
        ax2[r] = X2[ir]; ay2[r] = Y2[ir];
        aw[r]  = Wd[ir]; ah[r]  = Hd[ir];
        aarea[r] = aw[r] * ah[r];
    }
    unsigned long long myw0 = 0, myw1 = 0, myw2 = 0, myw3 = 0;
    for (int w = w0; w < nch; ++w) {
        int j = (w << 6) + lane;          // < mceil always (pad rows are zero)
        float bx1 = X1[j], by1 = Y1[j];
        float bx2 = X2[j], by2 = Y2[j];
        float bw  = Wd[j], bh  = Hd[j];
        float barea = bw * bh;
        bool jok = (j < M);
        #pragma unroll
        for (int r = 0; r < 4; ++r) {
            bool pred = false;
            if (jok && j > i0 + r) {
                float uw = fmaxf(ax2[r], bx2) - fminf(ax1[r], bx1);
                float uh = fmaxf(ay2[r], by2) - fminf(ay1[r], by1);
                float cw = aw[r] + bw - uw;
                float ch = ah[r] + bh - uh;
                if (cw > 0.0f && ch > 0.0f) {
                    float ca = cw * ch;
                    float ua = aarea[r] + barea - ca;
                    pred = ca > NMS_T * ua;          // iou > thresh
                }
            }
            unsigned long long m = __ballot(pred);
            if (w == lane) {
                if      (r == 0) myw0 = m;
                else if (r == 1) myw1 = m;
                else if (r == 2) myw2 = m;
                else             myw3 = m;
            }
        }
    }
    if (lane >= w0 && lane < nch) {
        // packed triangular: word lane holds rows [0, (lane+1)*64)
        unsigned long long* dst = supT + (size_t)b * TRIW + tri_off(lane);
        dst[i0] = myw0;
        if (i0 + 1 < M) dst[i0 + 1] = myw1;
        if (i0 + 2 < M) dst[i0 + 2] = myw2;
        if (i0 + 3 < M) dst[i0 + 3] = myw3;
    }
}

// ---- K3: 16-wave greedy sweep, two-barrier form. Owner-phase reduction via
// LDS atomicOr (independent pipelined ops, drained by lgkmcnt(0) at barrier)
// instead of a 12-deep serial ds_bpermute chain. Wave 0: readlane serial
// chain. GT match from LDS SoA. Finisher merged (done==7 protocol). ----
__global__ __launch_bounds__(1024, 1) void k_sweep(
    const float* __restrict__ soa, const float* __restrict__ tgt,
    const int* __restrict__ Marr, const unsigned long long* __restrict__ supT,
    int* __restrict__ counters, float* __restrict__ out)
{
    __shared__ float X1s[NBOXP], Y1s[NBOXP], X2s[NBOXP], Y2s[NBOXP];
    __shared__ float Wss[NBOXP], Hss[NBOXP];             // 44.5 KB
    __shared__ unsigned rmwU[2 * NWMAX];                 // lo/hi pairs
    __shared__ unsigned long long keepw[NWMAX];
    __shared__ int sNV, sCorr, sProp;
    const int b = blockIdx.x, tid = threadIdx.x;
    const int wv = tid >> 6, lane = tid & 63;
    const int M = Marr[b];
    const int nwa = (M + 63) >> 6;
    const unsigned long long* sb = supT + (size_t)b * TRIW;

    if (tid < 2 * NWMAX) rmwU[tid] = 0u;
    if (tid < NWMAX) keepw[tid] = 0ull;
    if (tid == 0) { sCorr = 0; sProp = 0; }

    // stage sorted SoA into LDS (only rows the sweep/GT can touch)
    {
        int mceil = (M + 63) & ~63;
        const float* X1 = soa + 0 * SOA_ARR + b * SOA_STRIDE;
        const float* Y1 = soa + 1 * SOA_ARR + b * SOA_STRIDE;
        const float* X2 = soa + 2 * SOA_ARR + b * SOA_STRIDE;
        const float* Y2 = soa + 3 * SOA_ARR + b * SOA_STRIDE;
        const float* Wd = soa + 4 * SOA_ARR + b * SOA_STRIDE;
        const float* Hd = soa + 5 * SOA_ARR + b * SOA_STRIDE;
        for (int p = tid; p < mceil; p += 1024) {
            X1s[p] = X1[p]; Y1s[p] = Y1[p];
            X2s[p] = X2[p]; Y2s[p] = Y2[p];
            Wss[p] = Wd[p]; Hss[p] = Hd[p];
        }
    }
    if (wv == 2) {       // GT count via ballot (first row with cx==0)
        float cxv = (lane < TMAX) ? tgt[b * 250 + lane * 5 + 1] : 0.0f;
        unsigned long long bm = __ballot(cxv != 0.0f);
        unsigned long long inv = (~bm) & ((1ull << TMAX) - 1ull);
        if (lane == 0) sNV = inv ? (__ffsll((long long)inv) - 1) : TMAX;
    }

    // static word ownership: wave wv owns {wv, wv+15} (covers words 1..28)
    const int w1 = (wv >= 1) ? wv : -1;
    const int w2 = (wv >= 1 && wv + 15 <= 28) ? (wv + 15) : -1;
    unsigned long long cur1 = 0, cur2 = 0, diag = 0;
    if (wv == 0 && nwa > 0) diag = sb[tri_off(0) + lane];            // tile0 diag
    if (w1 >= 1 && w1 < nwa) cur1 = sb[tri_off(w1) + lane];          // tile0 col
    if (w2 >= 1 && w2 < nwa) cur2 = sb[tri_off(w2) + lane];
    __syncthreads();     // staging + keepw/rmw init visible

    for (int t = 0; t < nwa; ++t) {
        if (wv == 0) {
            // serial greedy sweep for tile t: readlane chain
            unsigned long long cur =
                ((unsigned long long)rmwU[2 * t + 1] << 32) | rmwU[2 * t];
            int rem = M - (t << 6);
            unsigned long long vm = (rem >= 64) ? ~0ull : ((1ull << rem) - 1ull);
            unsigned long long live = vm & ~cur;
            while (live) {
                int i = __ffsll((long long)live) - 1;       // uniform
                unsigned long long w64 = rdlane64(diag, i);
                cur |= w64;
                live &= ~w64;
                live &= ~(1ull << i);
            }
            unsigned long long kp = vm & ~cur;
            if (lane == 0) keepw[t] = kp;
            int tn = t + 1;
            if (tn < nwa) diag = sb[tri_off(tn) + (tn << 6) + lane];
        }
        barrier_lgkm();                        // keepw[t] visible
        {
            unsigned long long kmt = keepw[t];
            bool kept = (kmt >> lane) & 1ull;
            if (w1 > t && w1 < nwa && kept) {
                unsigned lo = (unsigned)cur1, hi = (unsigned)(cur1 >> 32);
                if (lo) atomicOr(&rmwU[2 * w1], lo);
                if (hi) atomicOr(&rmwU[2 * w1 + 1], hi);
            }
            if (w2 > t && w2 < nwa && kept) {
                unsigned lo = (unsigned)cur2, hi = (unsigned)(cur2 >> 32);
                if (lo) atomicOr(&rmwU[2 * w2], lo);
                if (hi) atomicOr(&rmwU[2 * w2 + 1], hi);
            }
            // prefetch tile t+1 column — consumed after next sweep round
            if (w1 > t + 1 && w1 < nwa) cur1 = sb[tri_off(w1) + ((t + 1) << 6) + lane];
            if (w2 > t + 1 && w2 < nwa) cur2 = sb[tri_off(w2) + ((t + 1) << 6) + lane];
        }
        barrier_lgkm();                        // rmw atomics drained + visible
    }

    // proposals
    if (wv == 0) {
        unsigned long long kv = (lane < NWMAX) ? keepw[lane] : 0ull;
        int pc = __popcll(kv);
        for (int d = 32; d > 0; d >>= 1) pc += __shfl_down(pc, d, 64);
        if (lane == 0) sProp = pc;
    }

    // GT matching: 16 waves, branchless, LDS SoA; skip empty keep-words
    const int nv = sNV;
    for (int t = wv; t < nv; t += 16) {
        const float* g = tgt + b * 250 + t * 5;
        float gcx = g[1], gcy = g[2], gw = g[3], gh = g[4];
        float gx1 = gcx - 0.5f * gw, gx2 = gcx + 0.5f * gw;
        float gy1 = gcy - 0.5f * gh, gy2 = gcy + 0.5f * gh;
        float garea = gw * gh;
        float best = 0.0f;
        for (int j0 = 0; j0 < M; j0 += 64) {
            unsigned long long kw = keepw[j0 >> 6];
            if (kw == 0ull) continue;          // wave-uniform skip
            int j = j0 + lane;
            bool ok = (j < M) && ((kw >> lane) & 1ull);
            int js = (j < NBOXP) ? j : (NBOXP - 1);
            float bw = Wss[js], bh = Hss[js];
            float uw = fmaxf(gx2, X2s[js]) - fminf(gx1, X1s[js]);
            float uh = fmaxf(gy2, Y2s[js]) - fminf(gy1, Y1s[js]);
            float cww = gw + bw - uw, chh = gh + bh - uh;
            float ca = (cww > 0.0f && chh > 0.0f) ? cww * chh : 0.0f;
            float ua = garea + bw * bh - ca;
            float iou = ca / ua;
            best = fmaxf(best, ok ? iou : 0.0f);
        }
        for (int d = 32; d > 0; d >>= 1) best = fmaxf(best, __shfl_down(best, d, 64));
        if (lane == 0 && best > IOU_T) atomicAdd(&sCorr, 1);
    }
    barrier_lgkm();     // sProp/sCorr visible to tid 0

    // in-kernel finisher (protocol measured-correct in prior passing runs)
    if (tid == 0) {
        atomicAdd(counters + 0, sProp);
        atomicAdd(counters + 1, sCorr);
        atomicAdd(counters + 2, sNV);
        __threadfence();
        int done = atomicAdd(counters + 3, 1);
        if (done == 7) {
            float prop  = (float)atomicAdd(counters + 0, 0);
            float corr  = (float)atomicAdd(counters + 1, 0);
            float total = (float)atomicAdd(counters + 2, 0);
            float prec = corr / (prop + 1e-6f);
            float rec  = corr / (total + 1e-6f);
            float fs   = 2.0f * prec * rec / (prec + rec + 1e-6f);
            out[0] = total;
            out[1] = prop;
            out[2] = corr;
            out[3] = prec;
            out[4] = rec;
            out[5] = fs;
        }
    }
}

extern "C" void kernel_launch(void* const* d_in, const int* in_sizes, int n_in,
                              void* d_out, int out_size, void* d_ws, size_t ws_size,
                              hipStream_t stream) {
    const float* net = (const float*)d_in[0];   // [8,125,19,19] f32
    const float* tgt = (const float*)d_in[1];   // [8,250] f32
    char* ws = (char*)d_ws;
    int* counters = (int*)(ws + WS_COUNT);
    int* Marr     = (int*)(ws + WS_M);
    float* soa    = (float*)(ws + WS_SOA);
    unsigned long long* supT = (unsigned long long*)(ws + WS_SUP);

    k_decode_sort<<<8, NT1, 0, stream>>>(net, soa, Marr, counters);
    int rowblocks = (NBOX + 15) / 16;            // 113 groups of 16 rows
    k_iou_maskT<<<rowblocks * 8, 256, 0, stream>>>(soa, Marr, supT);
    k_sweep<<<8, 1024, 0, stream>>>(soa, tgt, Marr, supT, counters, (float*)d_out);
}

// Round 18
// 125.851 us; speedup vs baseline: 2.4844x; 1.0224x over previous
//
#include <hip/hip_runtime.h>

namespace {
constexpr int NA    = 5;
constexpr int NCELL = 361;            // 19*19
constexpr int NBOX  = 1805;           // NA * NCELL
constexpr int NBOXP = 1856;           // NBOX rounded up to 64
constexpr int NT1   = 1024;           // K1 threads (16 waves: hide sort barriers)
constexpr int TMAX  = 50;
constexpr float CONF_T = 0.5f;
constexpr float NMS_T  = 0.45f;
constexpr float IOU_T  = 0.5f;
constexpr int NW     = 29;            // max words (ceil(1805/64))
constexpr int NWMAX  = 32;            // rmw/keepw array size
constexpr int SOA_STRIDE = NBOXP;
constexpr int SOA_ARR    = 8 * SOA_STRIDE;
// packed triangular supT: word w holds rows [0, (w+1)*64) -> per-batch words
constexpr int TRIW = 64 * (NW * (NW + 1) / 2);   // 27840 words = 222,720 B
// ws layout (bytes)
constexpr size_t WS_COUNT = 0;        // 4 ints: prop, corr, total, done
constexpr size_t WS_M     = 64;       // 8 ints
constexpr size_t WS_SOA   = 256;      // 6 * SOA_ARR floats = 356,352 B
constexpr size_t WS_SUP   = 360448;   // 8 * TRIW * 8 = 1,781,760 B
__device__ inline size_t tri_off(int w) { return (size_t)32 * w * (w + 1); } // 64*w(w+1)/2
}

__device__ __constant__ float d_anchw[NA] = {1.3221f, 3.19275f, 5.05587f, 9.47112f, 11.2364f};
__device__ __constant__ float d_anchh[NA] = {1.73145f, 4.00944f, 8.09892f, 4.84053f, 10.0071f};

// uniform-index 64-bit readlane: ~3 cyc vs ~60-80 cyc for ds_bpermute shuffles
__device__ inline unsigned long long rdlane64(unsigned long long v, int l) {
    unsigned lo = (unsigned)__builtin_amdgcn_readlane((int)(unsigned)(v & 0xffffffffull), l);
    unsigned hi = (unsigned)__builtin_amdgcn_readlane((int)(unsigned)(v >> 32), l);
    return ((unsigned long long)hi << 32) | lo;
}
// Barrier that waits ONLY on LDS (lgkmcnt(0)); global prefetch loads stay in
// flight across the barrier. 0xC07F = vmcnt(63)|expcnt(7)|lgkmcnt(0).
__device__ inline void barrier_lgkm() {
    __asm__ volatile("" ::: "memory");
    __builtin_amdgcn_s_waitcnt(0xC07F);
    __builtin_amdgcn_s_barrier();
    __asm__ volatile("" ::: "memory");
}

// ---- K1: decode + conf-compaction + bitonic sort (S = pow2 >= M) + sorted
// zero-padded SoA to global. 1024 threads (16 waves). ----
__global__ __launch_bounds__(NT1, 1) void k_decode_sort(
    const float* __restrict__ net, float* __restrict__ soa,
    int* __restrict__ Marr, int* __restrict__ counters)
{
    __shared__ unsigned long long skey[2048];    // 16 KB
    __shared__ float4 sbox[NBOX];                // 28.9 KB
    __shared__ int sCnt;
    const int b = blockIdx.x, tid = threadIdx.x, lane = tid & 63;
    const float* op = net + (size_t)b * (NA * 25 * NCELL);
    if (tid == 0) sCnt = 0;
    if (b == 0 && tid < 4) counters[tid] = 0;    // K3 finisher state (stream-ordered)
    __syncthreads();

    // decode + compaction: only det>CONF_T enter the sort (invalid boxes never
    // suppress, are never counted as proposals, never match GT)
    for (int n = tid; n < NBOX; n += NT1) {
        int a = n / NCELL;
        int r = n - a * NCELL;
        int y = r / 19;
        int x = r - y * 19;
        int base = a * 25 * NCELL + r;
        float t0 = op[base];
        float t1 = op[base + 1 * NCELL];
        float t2 = op[base + 2 * NCELL];
        float t3 = op[base + 3 * NCELL];
        float t4 = op[base + 4 * NCELL];
        float cx = (1.0f / (1.0f + expf(-t0)) + (float)x) / 19.0f;
        float cy = (1.0f / (1.0f + expf(-t1)) + (float)y) / 19.0f;
        float bw = expf(t2) * (d_anchw[a] / 19.0f);
        float bh = expf(t3) * (d_anchh[a] / 19.0f);
        float det = 1.0f / (1.0f + expf(-t4));
        sbox[n] = make_float4(cx, cy, bw, bh);
        bool valid = det > CONF_T;
        unsigned long long bm = __ballot(valid);
        int base0 = 0;
        if (lane == 0 && bm) base0 = atomicAdd(&sCnt, __popcll(bm));
        base0 = __shfl(base0, 0, 64);
        if (valid) {
            int pos = base0 + __popcll(bm & ((1ull << lane) - 1ull));
            // det desc; ties broken by original index n asc (matches stable argsort)
            skey[pos] = ((unsigned long long)(~__float_as_uint(det)) << 32) | (unsigned)n;
        }
    }
    __syncthreads();
    const int M = sCnt;
    int S = 64; while (S < M) S <<= 1;            // <= 2048
    for (int n = M + tid; n < S; n += NT1) skey[n] = ~0ull;
    __syncthreads();

    // bitonic sort of S keys; 8-key register blocks handle j<=4 phases
    unsigned long long v[8];
    const int nt8 = S >> 3;                       // threads doing 8-key blocks
    const int base8 = tid << 3;
    auto cas = [&](int xx, int yy, bool up) {
        unsigned long long a = v[xx], c = v[yy];
        if ((a > c) == up) { v[xx] = c; v[yy] = a; }
    };
    if (tid < nt8) {
        #pragma unroll
        for (int p = 0; p < 8; ++p) v[p] = skey[base8 + p];
        cas(0,1,true); cas(2,3,false); cas(4,5,true); cas(6,7,false);
        cas(0,2,true); cas(1,3,true); cas(4,6,false); cas(5,7,false);
        cas(0,1,true); cas(2,3,true); cas(4,5,false); cas(6,7,false);
        bool u8 = ((base8 & 8) == 0);
        cas(0,4,u8); cas(1,5,u8); cas(2,6,u8); cas(3,7,u8);
        cas(0,2,u8); cas(1,3,u8); cas(4,6,u8); cas(5,7,u8);
        cas(0,1,u8); cas(2,3,u8); cas(4,5,u8); cas(6,7,u8);
        #pragma unroll
        for (int p = 0; p < 8; ++p) skey[base8 + p] = v[p];
    }
    __syncthreads();
    for (unsigned k = 16; k <= (unsigned)S; k <<= 1) {
        for (unsigned j = k >> 1; j >= 8; j >>= 1) {
            for (unsigned m = tid; m < (unsigned)(S >> 1); m += NT1) {
                unsigned i = ((m & ~(j - 1)) << 1) | (m & (j - 1));
                unsigned p = i | j;
                bool up = ((i & k) == 0);
                unsigned long long a = skey[i], c2 = skey[p];
                if ((a > c2) == up) { skey[i] = c2; skey[p] = a; }
            }
            __syncthreads();
        }
        if (tid < nt8) {
            #pragma unroll
            for (int p = 0; p < 8; ++p) v[p] = skey[base8 + p];
            bool up = ((base8 & k) == 0);
            cas(0,4,up); cas(1,5,up); cas(2,6,up); cas(3,7,up);
            cas(0,2,up); cas(1,3,up); cas(4,6,up); cas(5,7,up);
            cas(0,1,up); cas(2,3,up); cas(4,5,up); cas(6,7,up);
            #pragma unroll
            for (int p = 0; p < 8; ++p) skey[base8 + p] = v[p];
        }
        __syncthreads();
    }

    // sorted SoA to global, zero-padded to mceil (K2/K3 read pad rows freely)
    float* X1 = soa + 0 * SOA_ARR + b * SOA_STRIDE;
    float* Y1 = soa + 1 * SOA_ARR + b * SOA_STRIDE;
    float* X2 = soa + 2 * SOA_ARR + b * SOA_STRIDE;
    float* Y2 = soa + 3 * SOA_ARR + b * SOA_STRIDE;
    float* Wd = soa + 4 * SOA_ARR + b * SOA_STRIDE;
    float* Hd = soa + 5 * SOA_ARR + b * SOA_STRIDE;
    const int mceil = (M + 63) & ~63;
    for (int p = tid; p < mceil; p += NT1) {
        float4 bx = make_float4(0.f, 0.f, 0.f, 0.f);
        if (p < M) bx = sbox[(unsigned)(skey[p] & 0xffffffffull)];
        X1[p] = bx.x - 0.5f * bx.z;
        Y1[p] = bx.y - 0.5f * bx.w;
        X2[p] = bx.x + 0.5f * bx.z;
        Y2[p] = bx.y + 0.5f * bx.w;
        Wd[p] = bx.z;
        Hd[p] = bx.w;
    }
    if (tid == 0) Marr[b] = M;
}

// ---- K2: suppression words, chip-wide, packed-triangular store. 16 rows/
// block (4 rows/wave, column data loaded once per wave, reused 4x).
// Triangular skip: word w < row>>6 is never read by k_sweep. ----
__global__ __launch_bounds__(256) void k_iou_maskT(
    const float* __restrict__ soa, const int* __restrict__ Marr,
    unsigned long long* __restrict__ supT)
{
    const int blk  = blockIdx.x;
    const int b    = blk & 7;             // batch -> stable XCD under round-robin
    const int g    = blk >> 3;            // 16-row group
    const int wv   = threadIdx.x >> 6;
    const int lane = threadIdx.x & 63;
    const int M = Marr[b];
    const int i0 = g * 16 + wv * 4;       // this wave's first row
    if (i0 >= M) return;                  // per-wave exit (no barriers below)
    const float* X1 = soa + 0 * SOA_ARR + b * SOA_STRIDE;
    const float* Y1 = soa + 1 * SOA_ARR + b * SOA_STRIDE;
    const float* X2 = soa + 2 * SOA_ARR + b * SOA_STRIDE;
    const float* Y2 = soa + 3 * SOA_ARR + b * SOA_STRIDE;
    const float* Wd = soa + 4 * SOA_ARR + b * SOA_STRIDE;
    const float* Hd = soa + 5 * SOA_ARR + b * SOA_STRIDE;
    const int nch = (M + 63) >> 6;
    const int w0  = i0 >> 6;              // rows i0..i0+3 share i>>6 (4 | 64)

    float ax1[4], ay1[4], ax2[4], ay2[4], aw[4], ah[4], aarea[4];
    #pragma unroll
    for (int r = 0; r < 4; ++r) {
        int ir = i0 + r; if (ir >= M) ir = M - 1;   // clamp; masked at store
        ax1[r] = X1[ir]; ay1[r] = Y1[ir];
        ax2[r] = X2[ir]; ay2[r] = Y2[ir];
        aw[r]  = Wd[ir]; ah[r]  = Hd[ir];
        aarea[r] = aw[r] * ah[r];
    }
    unsigned long long myw0 = 0, myw1 = 0, myw2 = 0, myw3 = 0;
    for (int w = w0; w < nch; ++w) {
        int j = (w << 6) + lane;          // < mceil always (pad rows are zero)
        float bx1 = X1[j], by1 = Y1[j];
        float bx2 = X2[j], by2 = Y2[j];
        float bw  = Wd[j], bh  = Hd[j];
        float barea = bw * bh;
        bool jok = (j < M);
        #pragma unroll
        for (int r = 0; r < 4; ++r) {
            bool pred = false;
            if (jok && j > i0 + r) {
                float uw = fmaxf(ax2[r], bx2) - fminf(ax1[r], bx1);
                float uh = fmaxf(ay2[r], by2) - fminf(ay1[r], by1);
                float cw = aw[r] + bw - uw;
                float ch = ah[r] + bh - uh;
                if (cw > 0.0f && ch > 0.0f) {
                    float ca = cw * ch;
                    float ua = aarea[r] + barea - ca;
                    pred = ca > NMS_T * ua;          // iou > thresh
                }
            }
            unsigned long long m = __ballot(pred);
            if (w == lane) {
                if      (r == 0) myw0 = m;
                else if (r == 1) myw1 = m;
                else if (r == 2) myw2 = m;
                else             myw3 = m;
            }
        }
    }
    if (lane >= w0 && lane < nch) {
        // packed triangular: word lane holds rows [0, (lane+1)*64)
        unsigned long long* dst = supT + (size_t)b * TRIW + tri_off(lane);
        dst[i0] = myw0;
        if (i0 + 1 < M) dst[i0 + 1] = myw1;
        if (i0 + 2 < M) dst[i0 + 2] = myw2;
        if (i0 + 3 < M) dst[i0 + 3] = myw3;
    }
}

// ---- K3: 16-wave greedy sweep, TWO WORDS PER ROUND (barriers 30 -> ~16).
// Wave 0 per round r (tiles tA=2r, tB=2r+1): sweep tile A with registers
// dAA (intra-A) and dAB (A-rows -> B-word, accumulated off the ffs chain into
// nxtB), then sweep tile B from rmw[tB]|nxtB with dBB. Owner waves apply
// keepA/keepB via LDS atomicOr to words >= 2r+2 only (word tB handled
// in-round by nxtB). Hazard: words 2r+2, 2r+3 last written POST(r), read
// PRE(r+1), separated by B2(r) whose lgkmcnt(0) drains the atomics. ----
__global__ __launch_bounds__(1024, 1) void k_sweep(
    const float* __restrict__ soa, const float* __restrict__ tgt,
    const int* __restrict__ Marr, const unsigned long long* __restrict__ supT,
    int* __restrict__ counters, float* __restrict__ out)
{
    __shared__ float X1s[NBOXP], Y1s[NBOXP], X2s[NBOXP], Y2s[NBOXP];
    __shared__ float Wss[NBOXP], Hss[NBOXP];             // 44.5 KB
    __shared__ unsigned rmwU[2 * NWMAX];                 // lo/hi pairs
    __shared__ unsigned long long keepw[NWMAX];
    __shared__ int sNV, sCorr, sProp;
    const int b = blockIdx.x, tid = threadIdx.x;
    const int wv = tid >> 6, lane = tid & 63;
    const int M = Marr[b];
    const int nwa = (M + 63) >> 6;
    const unsigned long long* sb = supT + (size_t)b * TRIW;

    if (tid < 2 * NWMAX) rmwU[tid] = 0u;
    if (tid < NWMAX) keepw[tid] = 0ull;
    if (tid == 0) { sCorr = 0; sProp = 0; }

    // stage sorted SoA into LDS (only rows the sweep/GT can touch)
    {
        int mceil = (M + 63) & ~63;
        const float* X1 = soa + 0 * SOA_ARR + b * SOA_STRIDE;
        const float* Y1 = soa + 1 * SOA_ARR + b * SOA_STRIDE;
        const float* X2 = soa + 2 * SOA_ARR + b * SOA_STRIDE;
        const float* Y2 = soa + 3 * SOA_ARR + b * SOA_STRIDE;
        const float* Wd = soa + 4 * SOA_ARR + b * SOA_STRIDE;
        const float* Hd = soa + 5 * SOA_ARR + b * SOA_STRIDE;
        for (int p = tid; p < mceil; p += 1024) {
            X1s[p] = X1[p]; Y1s[p] = Y1[p];
            X2s[p] = X2[p]; Y2s[p] = Y2[p];
            Wss[p] = Wd[p]; Hss[p] = Hd[p];
        }
    }
    if (wv == 2) {       // GT count via ballot (first row with cx==0)
        float cxv = (lane < TMAX) ? tgt[b * 250 + lane * 5 + 1] : 0.0f;
        unsigned long long bm = __ballot(cxv != 0.0f);
        unsigned long long inv = (~bm) & ((1ull << TMAX) - 1ull);
        if (lane == 0) sNV = inv ? (__ffsll((long long)inv) - 1) : TMAX;
    }

    // static word ownership: wave wv owns {wv, wv+15} (covers words 1..28)
    const int w1 = (wv >= 1) ? wv : -1;
    const int w2 = (wv >= 1 && wv + 15 <= 28) ? (wv + 15) : -1;
    // wave-0 round-0 registers: dAA=rows0-63 word0, dAB=rows0-63 word1,
    // dBB=rows64-127 word1. Owner columns for round 0 rows.
    unsigned long long dAA = 0, dAB = 0, dBB = 0;
    unsigned long long curA1 = 0, curB1 = 0, curA2 = 0, curB2 = 0;
    if (wv == 0 && nwa > 0) {
        dAA = sb[tri_off(0) + lane];
        if (nwa > 1) {
            dAB = sb[tri_off(1) + lane];
            dBB = sb[tri_off(1) + 64 + lane];
        }
    }
    if (w1 >= 1 && w1 < nwa) {
        curA1 = sb[tri_off(w1) + lane];
        curB1 = sb[tri_off(w1) + 64 + lane];
    }
    if (w2 >= 1 && w2 < nwa) {
        curA2 = sb[tri_off(w2) + lane];
        curB2 = sb[tri_off(w2) + 64 + lane];
    }
    __syncthreads();     // staging + keepw/rmw init visible

    const int nr = (nwa + 1) >> 1;       // rounds of 2 tiles
    for (int r = 0; r < nr; ++r) {
        const int tA = 2 * r, tB = 2 * r + 1;
        if (wv == 0) {
            // PRE(r): sweep tile A, carry into tile B in-register
            unsigned long long curA =
                ((unsigned long long)rmwU[2 * tA + 1] << 32) | rmwU[2 * tA];
            int remA = M - (tA << 6);
            unsigned long long vmA = (remA >= 64) ? ~0ull : ((1ull << remA) - 1ull);
            unsigned long long liveA = vmA & ~curA;
            unsigned long long nxtB = 0;
            while (liveA) {
                int i = __ffsll((long long)liveA) - 1;        // uniform
                unsigned long long wA = rdlane64(dAA, i);
                unsigned long long wB = rdlane64(dAB, i);     // off ffs chain
                curA |= wA;
                nxtB |= wB;
                liveA &= ~wA;
                liveA &= ~(1ull << i);
            }
            unsigned long long keepA = vmA & ~curA;
            if (lane == 0) keepw[tA] = keepA;
            if (tB < nwa) {
                unsigned long long curB =
                    (((unsigned long long)rmwU[2 * tB + 1] << 32) | rmwU[2 * tB]) | nxtB;
                int remB = M - (tB << 6);
                unsigned long long vmB = (remB >= 64) ? ~0ull : ((1ull << remB) - 1ull);
                unsigned long long liveB = vmB & ~curB;
                while (liveB) {
                    int i = __ffsll((long long)liveB) - 1;    // uniform
                    unsigned long long wB = rdlane64(dBB, i);
                    curB |= wB;
                    liveB &= ~wB;
                    liveB &= ~(1ull << i);
                }
                if (lane == 0) keepw[tB] = vmB & ~curB;
            }
            // prefetch next round's register columns (consumed PRE(r+1))
            int nA = tA + 2, nB = tA + 3;
            if (nA < nwa) {
                dAA = sb[tri_off(nA) + (nA << 6) + lane];
                if (nB < nwa) {
                    dAB = sb[tri_off(nB) + (nA << 6) + lane];
                    dBB = sb[tri_off(nB) + (nB << 6) + lane];
                } else { dAB = 0; dBB = 0; }
            }
        }
        barrier_lgkm();                        // keepw[tA],keepw[tB] visible
        {
            // POST(r): owners apply keepA/keepB to owned words >= 2r+2
            unsigned long long kmtA = keepw[tA];
            unsigned long long kmtB = (tB < nwa) ? keepw[tB] : 0ull;
            bool keptA = (kmtA >> lane) & 1ull;
            bool keptB = (kmtB >> lane) & 1ull;
            if (w1 > tB && w1 < nwa) {
                if (keptA) {
                    unsigned lo = (unsigned)curA1, hi = (unsigned)(curA1 >> 32);
                    if (lo) atomicOr(&rmwU[2 * w1], lo);
                    if (hi) atomicOr(&rmwU[2 * w1 + 1], hi);
                }
                if (keptB) {
                    unsigned lo = (unsigned)curB1, hi = (unsigned)(curB1 >> 32);
                    if (lo) atomicOr(&rmwU[2 * w1], lo);
                    if (hi) atomicOr(&rmwU[2 * w1 + 1], hi);
                }
            }
            if (w2 > tB && w2 < nwa) {
                if (keptA) {
                    unsigned lo = (unsigned)curA2, hi = (unsigned)(curA2 >> 32);
                    if (lo) atomicOr(&rmwU[2 * w2], lo);
                    if (hi) atomicOr(&rmwU[2 * w2 + 1], hi);
                }
                if (keptB) {
                    unsigned lo = (unsigned)curB2, hi = (unsigned)(curB2 >> 32);
                    if (lo) atomicOr(&rmwU[2 * w2], lo);
                    if (hi) atomicOr(&rmwU[2 * w2 + 1], hi);
                }
            }
            // prefetch next round's columns (rows of tiles 2r+2, 2r+3);
            // consumed POST(r+1) only when w > 2r+3 -> guard matches bounds
            int nA = tA + 2, nB = tA + 3;
            if (w1 > nB && w1 < nwa) {
                curA1 = sb[tri_off(w1) + (nA << 6) + lane];
                curB1 = sb[tri_off(w1) + (nB << 6) + lane];
            }
            if (w2 > nB && w2 < nwa) {
                curA2 = sb[tri_off(w2) + (nA << 6) + lane];
                curB2 = sb[tri_off(w2) + (nB << 6) + lane];
            }
        }
        barrier_lgkm();                        // rmw atomics drained + visible
    }

    // proposals
    if (wv == 0) {
        unsigned long long kv = (lane < NWMAX) ? keepw[lane] : 0ull;
        int pc = __popcll(kv);
        for (int d = 32; d > 0; d >>= 1) pc += __shfl_down(pc, d, 64);
        if (lane == 0) sProp = pc;
    }

    // GT matching: 16 waves, branchless, LDS SoA; skip empty keep-words
    const int nv = sNV;
    for (int t = wv; t < nv; t += 16) {
        const float* g = tgt + b * 250 + t * 5;
        float gcx = g[1], gcy = g[2], gw = g[3], gh = g[4];
        float gx1 = gcx - 0.5f * gw, gx2 = gcx + 0.5f * gw;
        float gy1 = gcy - 0.5f * gh, gy2 = gcy + 0.5f * gh;
        float garea = gw * gh;
        float best = 0.0f;
        for (int j0 = 0; j0 < M; j0 += 64) {
            unsigned long long kw = keepw[j0 >> 6];
            if (kw == 0ull) continue;          // wave-uniform skip
            int j = j0 + lane;
            bool ok = (j < M) && ((kw >> lane) & 1ull);
            int js = (j < NBOXP) ? j : (NBOXP - 1);
            float bw = Wss[js], bh = Hss[js];
            float uw = fmaxf(gx2, X2s[js]) - fminf(gx1, X1s[js]);
            float uh = fmaxf(gy2, Y2s[js]) - fminf(gy1, Y1s[js]);
            float cww = gw + bw - uw, chh = gh + bh - uh;
            float ca = (cww > 0.0f && chh > 0.0f) ? cww * chh : 0.0f;
            float ua = garea + bw * bh - ca;
            float iou = ca / ua;
            best = fmaxf(best, ok ? iou : 0.0f);
        }
        for (int d = 32; d > 0; d >>= 1) best = fmaxf(best, __shfl_down(best, d, 64));
        if (lane == 0 && best > IOU_T) atomicAdd(&sCorr, 1);
    }
    barrier_lgkm();     // sProp/sCorr visible to tid 0

    // in-kernel finisher (protocol measured-correct in prior passing runs)
    if (tid == 0) {
        atomicAdd(counters + 0, sProp);
        atomicAdd(counters + 1, sCorr);
        atomicAdd(counters + 2, sNV);
        __threadfence();
        int done = atomicAdd(counters + 3, 1);
        if (done == 7) {
            float prop  = (float)atomicAdd(counters + 0, 0);
            float corr  = (float)atomicAdd(counters + 1, 0);
            float total = (float)atomicAdd(counters + 2, 0);
            float prec = corr / (prop + 1e-6f);
            float rec  = corr / (total + 1e-6f);
            float fs   = 2.0f * prec * rec / (prec + rec + 1e-6f);
            out[0] = total;
            out[1] = prop;
            out[2] = corr;
            out[3] = prec;
            out[4] = rec;
            out[5] = fs;
        }
    }
}

extern "C" void kernel_launch(void* const* d_in, const int* in_sizes, int n_in,
                              void* d_out, int out_size, void* d_ws, size_t ws_size,
                              hipStream_t stream) {
    const float* net = (const float*)d_in[0];   // [8,125,19,19] f32
    const float* tgt = (const float*)d_in[1];   // [8,250] f32
    char* ws = (char*)d_ws;
    int* counters = (int*)(ws + WS_COUNT);
    int* Marr     = (int*)(ws + WS_M);
    float* soa    = (float*)(ws + WS_SOA);
    unsigned long long* supT = (unsigned long long*)(ws + WS_SUP);

    k_decode_sort<<<8, NT1, 0, stream>>>(net, soa, Marr, counters);
    int rowblocks = (NBOX + 15) / 16;            // 113 groups of 16 rows
    k_iou_maskT<<<rowblocks * 8, 256, 0, stream>>>(soa, Marr, supT);
    k_sweep<<<8, 1024, 0, stream>>>(soa, tgt, Marr, supT, counters, (float*)d_out);
}